// Round 12
// baseline (261.700 us; speedup 1.0000x reference)
//
#include <hip/hip_runtime.h>

// ---------------------------------------------------------------------------
// Causal self-attention block, B=1 T=4096 C=768 H=12 D=64, fp32 in/out.
// bf16 MFMA everywhere; flash attention without online max (scores bounded,
// log2-domain) -> s-chunks combine by pure summation (NO atomics: R4/R5).
// R22: deferred-PV via MACRO (no lambdas). R19's scratch disaster was the
// [&]-capturing lambdas holding carried pfp/vfp arrays (closure pointer ->
// scratch; VGPR pinned 84, FETCH 15->167MB). Macro = textual expansion, no
// closure: pfp[2][2]/vfp[2][4] are plain locals with constant indices ->
// SROA keeps them in VGPRs. Schedule: PV(i-1) reg-only at top of phase i,
// back-to-back with QK(i) MFMAs; softmax VALU off PV's critical path.
// Body = R21 swapped-QK (P b64 writes, 2-float rsum) + R13 2-phase static
// dbuf. Spill detector: VGPR must rise to ~130, FETCH must stay 15.3MB.
// Ledger: R13 dbuf(+), R15 2-chunk(+), R21 swapped-QK(+, 156.6us best).
// Failed: R11 dyn-idx, R12 direct-KV, R14 128^2, R18 direct-V, R19 lambda.
// ---------------------------------------------------------------------------

#define T_SEQ 4096
#define C_EMB 768
#define NH    12
#define HD    64

typedef __attribute__((ext_vector_type(8))) short bf16x8;   // 8 bf16 = 4 VGPRs
typedef __attribute__((ext_vector_type(4))) float floatx4;  // MFMA C/D

// 0.125 (1/sqrt(64)) * log2(e): folded into Q so scores are log2-domain.
#define QSCALE 0.18033688011112042f

__device__ __forceinline__ unsigned short f2bf(float f) {
  union { float f; unsigned u; } v; v.f = f;
  unsigned r = v.u + 0x7fffu + ((v.u >> 16) & 1u);  // RNE
  return (unsigned short)(r >> 16);
}
// round-half-up, valid for f >= 0 (used for P probabilities)
__device__ __forceinline__ unsigned short f2bf_rhu(float f) {
  union { float f; unsigned u; } v; v.f = f;
  return (unsigned short)((v.u + 0x8000u) >> 16);
}
__device__ __forceinline__ float bf2f(unsigned short h) {
  union { unsigned u; float f; } v; v.u = ((unsigned)h) << 16;
  return v.f;
}

// async global->LDS, 16B/lane. LDS dest is wave-uniform base + lane*16.
__device__ __forceinline__ void gload_lds16(const void* gptr, void* ldsptr) {
  __builtin_amdgcn_global_load_lds(
      (const __attribute__((address_space(1))) unsigned int*)gptr,
      (__attribute__((address_space(3))) unsigned int*)ldsptr,
      16, 0, 0);
}

// ---------------------------------------------------------------------------
// Single fused cast (known-good): [x|wq|wk|wv|wo] fp32 -> contiguous bf16.
// ---------------------------------------------------------------------------
__global__ void cast_all_kernel(const float* __restrict__ x,
                                const float* __restrict__ wq,
                                const float* __restrict__ wk,
                                const float* __restrict__ wv,
                                const float* __restrict__ wo,
                                unsigned short* __restrict__ dst) {
  const int GX = (T_SEQ * C_EMB) / 4;
  const int GW = (C_EMB * C_EMB) / 4;
  int i = blockIdx.x * blockDim.x + threadIdx.x;
  const float* src; int local;
  if (i < GX) { src = x; local = i; }
  else {
    int t = i - GX; int w = t / GW; local = t - w * GW;
    src = (w == 0) ? wq : (w == 1) ? wk : (w == 2) ? wv : wo;
  }
  float4 f = reinterpret_cast<const float4*>(src)[local];
  ushort4 u;
  u.x = f2bf(f.x); u.y = f2bf(f.y); u.z = f2bf(f.z); u.w = f2bf(f.w);
  reinterpret_cast<ushort4*>(dst)[i] = u;
}

// ---------------------------------------------------------------------------
// QKV GEMM (R17): 64x128 tile, BK=64, 2-phase static-dbuf K-loop.
// C[m][n] = sum_k X[m][k]*Wqkv[n][k]  (M=4096, N=2304, K=768)
// -> 64 x 18 = 1152 blocks, 12 K-steps, LDS 48 KB (3 blocks/CU).
// ---------------------------------------------------------------------------
__global__ __launch_bounds__(256) void gemm_qkv(
    const unsigned short* __restrict__ A,
    const unsigned short* __restrict__ B,
    unsigned short* __restrict__ Qb,
    unsigned short* __restrict__ Kb,
    unsigned short* __restrict__ Vt) {
  constexpr int K = 768, BM = 64, BN = 128, BK = 64;
  __shared__ __align__(16) unsigned short As0[BM * BK];  // 8 KB
  __shared__ __align__(16) unsigned short Bs0[BN * BK];  // 16 KB
  __shared__ __align__(16) unsigned short As1[BM * BK];  // 8 KB
  __shared__ __align__(16) unsigned short Bs1[BN * BK];  // 16 KB
  const int tid = threadIdx.x;
  const int wave = tid >> 6, lane = tid & 63;
  const int lm = lane & 15, lq = lane >> 4;
  const int swz = lm & 7;
  const int m0 = blockIdx.x * BM, n0 = blockIdx.y * BN;
  const int wm = (wave & 1) * 32, wn = (wave >> 1) * 64;
  floatx4 acc[2][4] = {};

  auto stage = [&](int k0, unsigned short* Ad, unsigned short* Bd) {
#pragma unroll
    for (int i = 0; i < 2; i++) {             // A: 512 chunks (64 rows x 8)
      int idx = i * 256 + tid;
      int row = idx >> 3;
      int ch = (idx & 7) ^ (row & 7);
      gload_lds16(A + (size_t)(m0 + row) * K + k0 + ch * 8, (char*)Ad + idx * 16);
    }
#pragma unroll
    for (int i = 0; i < 4; i++) {             // B: 1024 chunks (128 rows x 8)
      int idx = i * 256 + tid;
      int row = idx >> 3;
      int ch = (idx & 7) ^ (row & 7);
      gload_lds16(B + (size_t)(n0 + row) * K + k0 + ch * 8, (char*)Bd + idx * 16);
    }
  };

  auto compute = [&](const unsigned short* Asb, const unsigned short* Bsb) {
#pragma unroll
    for (int kk = 0; kk < 2; kk++) {
      bf16x8 af[2], bfr[4];
#pragma unroll
      for (int i = 0; i < 2; i++) {
        int row = wm + i * 16 + lm;
        af[i] = *(const bf16x8*)(Asb + row * BK + (((kk * 4 + lq) ^ swz) * 8));
      }
#pragma unroll
      for (int j = 0; j < 4; j++) {
        int row = wn + j * 16 + lm;
        bfr[j] = *(const bf16x8*)(Bsb + row * BK + (((kk * 4 + lq) ^ swz) * 8));
      }
#pragma unroll
      for (int i = 0; i < 2; i++)
#pragma unroll
        for (int j = 0; j < 4; j++)
          acc[i][j] = __builtin_amdgcn_mfma_f32_16x16x32_bf16(af[i], bfr[j], acc[i][j], 0, 0, 0);
    }
  };

  stage(0, As0, Bs0);
  int k0 = 0;
  while (true) {
    __syncthreads();                        // buf0 staged; buf1 reads done
    if (k0 + BK < K) stage(k0 + BK, As1, Bs1);
    compute(As0, Bs0);
    k0 += BK; if (k0 >= K) break;
    __syncthreads();                        // buf1 staged; buf0 reads done
    if (k0 + BK < K) stage(k0 + BK, As0, Bs0);
    compute(As1, Bs1);
    k0 += BK; if (k0 >= K) break;
  }

  const int which = n0 / C_EMB;                   // block-uniform (128 | 768)
  if (which < 2) {
    unsigned short* tgt = (which == 0) ? Qb : Kb;
    const float sc = (which == 0) ? QSCALE : 1.0f;
#pragma unroll
    for (int i = 0; i < 2; i++)
#pragma unroll
      for (int j = 0; j < 4; j++) {
        int n = n0 - which * C_EMB + wn + j * 16 + lm;
        int h = n >> 6, d = n & 63;
#pragma unroll
        for (int r = 0; r < 4; r++) {
          int m = m0 + wm + i * 16 + lq * 4 + r;
          tgt[(((size_t)h * T_SEQ + m) << 6) + d] = f2bf(acc[i][j][r] * sc);
        }
      }
  } else {
#pragma unroll
    for (int i = 0; i < 2; i++)
#pragma unroll
      for (int j = 0; j < 4; j++) {
        int n = n0 - 2 * C_EMB + wn + j * 16 + lm;
        int h = n >> 6, d = n & 63;
        int m = m0 + wm + i * 16 + lq * 4;
        ushort4 pk;
        pk.x = f2bf(acc[i][j][0]); pk.y = f2bf(acc[i][j][1]);
        pk.z = f2bf(acc[i][j][2]); pk.w = f2bf(acc[i][j][3]);
        *(ushort4*)(Vt + ((size_t)(h * HD + d)) * T_SEQ + m) = pk;
      }
  }
}

// ---------------------------------------------------------------------------
// Shared attention inner body (R22): swapped-QK (R21) + deferred-PV via
// macro. pfp/vfp are PLAIN LOCALS (no lambda capture -> no closure ->
// registers). Phase: QK(it) MFMAs; PV(it-1) reg-only (independent, same
// block); mask; softmax + b64 P-write; read pfp (P LDS) + vfp (Vs) for the
// NEXT phase. vfp read before the next barrier; that V buffer is only
// re-staged a phase later (reads drained at the intervening barrier).
// ---------------------------------------------------------------------------
struct AttnState {
  float rsum[2];
  floatx4 o_acc[2][4];
};

// The phase macro: textual expansion into attn_body's scope; every array
// index is a compile-time constant after unrolling.
#define ATTN_PHASE(Kc, Vc, DO_PV, S0V)                                        \
  {                                                                           \
    const int s0_ = (S0V);                                                    \
    floatx4 sa[2][4] = {};                                                    \
    _Pragma("unroll")                                                         \
    for (int kk = 0; kk < 2; kk++)                                            \
      _Pragma("unroll")                                                       \
      for (int j = 0; j < 4; j++) {                                           \
        int row_ = j * 16 + lm;                                               \
        bf16x8 kf = *(const bf16x8*)((Kc) + (row_ * 8 + ((kk * 4 + lq) ^ swz)) * 8); \
        _Pragma("unroll")                                                     \
        for (int m = 0; m < 2; m++)                                           \
          sa[m][j] = __builtin_amdgcn_mfma_f32_16x16x32_bf16(kf, qf[m][kk], sa[m][j], 0, 0, 0); \
      }                                                                       \
    if (DO_PV) {                                                              \
      _Pragma("unroll")                                                       \
      for (int kk = 0; kk < 2; kk++)                                          \
        _Pragma("unroll")                                                     \
        for (int jd = 0; jd < 4; jd++)                                        \
          _Pragma("unroll")                                                   \
          for (int m = 0; m < 2; m++)                                         \
            st.o_acc[m][jd] = __builtin_amdgcn_mfma_f32_16x16x32_bf16(pfp[m][kk], vfp[kk][jd], st.o_acc[m][jd], 0, 0, 0); \
    }                                                                         \
    if (s0_ >= q0) {                                                          \
      _Pragma("unroll")                                                       \
      for (int m = 0; m < 2; m++) {                                           \
        int qrow_ = qrow_base + m * 16 + lm;                                  \
        _Pragma("unroll")                                                     \
        for (int j = 0; j < 4; j++)                                           \
          _Pragma("unroll")                                                   \
          for (int r = 0; r < 4; r++) {                                       \
            int scol_ = s0_ + j * 16 + lq * 4 + r;                            \
            if (scol_ > qrow_) sa[m][j][r] = -1e30f;                          \
          }                                                                   \
      }                                                                       \
    }                                                                         \
    _Pragma("unroll")                                                         \
    for (int m = 0; m < 2; m++)                                               \
      _Pragma("unroll")                                                       \
      for (int j = 0; j < 4; j++) {                                           \
        float p0 = __builtin_amdgcn_exp2f(sa[m][j][0]);                       \
        float p1 = __builtin_amdgcn_exp2f(sa[m][j][1]);                       \
        float p2 = __builtin_amdgcn_exp2f(sa[m][j][2]);                       \
        float p3 = __builtin_amdgcn_exp2f(sa[m][j][3]);                       \
        st.rsum[m] += (p0 + p1) + (p2 + p3);                                  \
        ushort4 pk;                                                           \
        pk.x = f2bf_rhu(p0); pk.y = f2bf_rhu(p1);                             \
        pk.z = f2bf_rhu(p2); pk.w = f2bf_rhu(p3);                             \
        *(ushort4*)(Pw + (m * 16 + lm) * PS + j * 16 + lq * 4) = pk;          \
      }                                                                       \
    _Pragma("unroll")                                                         \
    for (int kk = 0; kk < 2; kk++)                                            \
      _Pragma("unroll")                                                       \
      for (int m = 0; m < 2; m++)                                             \
        pfp[m][kk] = *(const bf16x8*)(Pw + (m * 16 + lm) * PS + kk * 32 + lq * 8); \
    _Pragma("unroll")                                                         \
    for (int kk = 0; kk < 2; kk++)                                            \
      _Pragma("unroll")                                                       \
      for (int jd = 0; jd < 4; jd++) {                                        \
        int row_ = jd * 16 + lm;                                              \
        vfp[kk][jd] = *(const bf16x8*)((Vc) + (row_ * 8 + ((kk * 4 + lq) ^ swz)) * 8); \
      }                                                                       \
  }

template <typename EpilogueFn>
__device__ __forceinline__ void attn_body(
    const unsigned short* __restrict__ Q,
    const unsigned short* __restrict__ K,
    const unsigned short* __restrict__ Vt,
    int h, int q0, int sb, int se,
    EpilogueFn epi) {
  constexpr int BS = 64, PS = 72, KVB = BS * HD;   // 4096 shorts per buffer
  __shared__ __align__(16) unsigned short Ks0[KVB];      // 8 KB
  __shared__ __align__(16) unsigned short Vs0[KVB];      // 8 KB
  __shared__ __align__(16) unsigned short Ks1[KVB];      // 8 KB
  __shared__ __align__(16) unsigned short Vs1[KVB];      // 8 KB
  __shared__ __align__(16) unsigned short Ps[4 * 32 * PS];  // 18 KB

  const int tid = threadIdx.x;
  const int wave = tid >> 6, lane = tid & 63;
  const int lm = lane & 15, lq = lane >> 4;
  const unsigned short* Qh = Q + (size_t)h * T_SEQ * HD;
  const unsigned short* Kh = K + (size_t)h * T_SEQ * HD;
  const unsigned short* Vh = Vt + (size_t)h * HD * T_SEQ;
  const int qrow_base = q0 + wave * 32;
  unsigned short* Pw = Ps + wave * 32 * PS;
  const int swz = lm & 7;

  bf16x8 qf[2][2];
#pragma unroll
  for (int m = 0; m < 2; m++)
#pragma unroll
    for (int kk = 0; kk < 2; kk++)
      qf[m][kk] = *(const bf16x8*)(Qh + (size_t)(qrow_base + m * 16 + lm) * HD + kk * 32 + lq * 8);

  AttnState st;
#pragma unroll
  for (int m = 0; m < 2; m++) {
    st.rsum[m] = 0.f;
#pragma unroll
    for (int r = 0; r < 4; r++) st.o_acc[m][r] = floatx4{0.f, 0.f, 0.f, 0.f};
  }

  // carried PV operands for the deferred step — plain locals, never captured
  bf16x8 pfp[2][2] = {};
  bf16x8 vfp[2][4] = {};

  auto stage = [&](int s0, unsigned short* Kd, unsigned short* Vd) {
#pragma unroll
    for (int i = 0; i < 2; i++) {
      int idx = (wave * 2 + i) * 64 + lane;
      int row = idx >> 3;
      int ch = (idx & 7) ^ (row & 7);
      gload_lds16(Kh + (size_t)(s0 + row) * HD + ch * 8, (char*)Kd + idx * 16);
      gload_lds16(Vh + (size_t)row * T_SEQ + s0 + ch * 8, (char*)Vd + idx * 16);
    }
  };

  // peeled first phase (no pending PV), then 2-phase alternation
  stage(sb * BS, Ks0, Vs0);
  int it = sb;
  __syncthreads();                          // buf0 staged
  if (it + 1 < se) stage((it + 1) * BS, Ks1, Vs1);
  ATTN_PHASE(Ks0, Vs0, false, it * BS);
  ++it;
  if (it < se) {
    while (true) {
      __syncthreads();                      // buf1 staged; buf0 reads done
      if (it + 1 < se) stage((it + 1) * BS, Ks0, Vs0);
      ATTN_PHASE(Ks1, Vs1, true, it * BS);
      if (++it >= se) break;
      __syncthreads();                      // buf0 staged; buf1 reads done
      if (it + 1 < se) stage((it + 1) * BS, Ks1, Vs1);
      ATTN_PHASE(Ks0, Vs0, true, it * BS);
      if (++it >= se) break;
    }
  }
  // final pending PV flush
#pragma unroll
  for (int kk = 0; kk < 2; kk++)
#pragma unroll
    for (int jd = 0; jd < 4; jd++)
#pragma unroll
      for (int m = 0; m < 2; m++)
        st.o_acc[m][jd] = __builtin_amdgcn_mfma_f32_16x16x32_bf16(pfp[m][kk], vfp[kk][jd], st.o_acc[m][jd], 0, 0, 0);

  // row-sum: per-lane partial covers s-cols {j*16+lq*4+r}; reduce across lq
#pragma unroll
  for (int m = 0; m < 2; m++) {
    float s = st.rsum[m];
    s += __shfl_xor(s, 16);
    s += __shfl_xor(s, 32);
    st.rsum[m] = s;
  }
  epi(st, qrow_base, lm, lq);
}

// ---------------------------------------------------------------------------
// Path A (R15, proven): 2 chunks, fp32 partials to exclusive slots.
// 768 blocks = exactly 3/CU (full residency); heavy q-tiles first.
// ---------------------------------------------------------------------------
__global__ __launch_bounds__(256, 3) void attn_kernelA(
    const unsigned short* __restrict__ Q,
    const unsigned short* __restrict__ K,
    const unsigned short* __restrict__ Vt,
    float* __restrict__ Opart,              // [2][12][4096][64] fp32
    float* __restrict__ lpart) {            // [2][12][4096] fp32
  const int bid = blockIdx.x;               // 0..767
  const int h = bid % NH;
  const int z = bid / NH;                   // 0..63
  const int qt = (T_SEQ / 128 - 1) - (z >> 1);  // heavy tiles first
  const int c = z & 1;
  const int q0 = qt * 128;
  const int sb = c ? (qt + 1) : 0;
  const int se = c ? (2 * qt + 2) : (qt + 1);

  const size_t CN = (size_t)NH * T_SEQ * HD;
  float* Oc = Opart + (size_t)c * CN;
  float* lc = lpart + (size_t)c * NH * T_SEQ;
  attn_body(Q, K, Vt, h, q0, sb, se,
    [&](const AttnState& st, int qrow_base, int lm, int lq) {
#pragma unroll
      for (int m = 0; m < 2; m++) {
        if (lq == 0) lc[h * T_SEQ + qrow_base + m * 16 + lm] = st.rsum[m];
#pragma unroll
        for (int r = 0; r < 4; r++) {
          int t = qrow_base + m * 16 + lq * 4 + r;
#pragma unroll
          for (int jd = 0; jd < 4; jd++)
            Oc[((size_t)h * T_SEQ + t) * HD + jd * 16 + lm] = st.o_acc[m][jd][r];
        }
      }
    });
}

__global__ void combine_kernelA(const float* __restrict__ Opart,
                                const float* __restrict__ lpart,
                                unsigned short* __restrict__ Ob) {
  int idx = blockIdx.x * blockDim.x + threadIdx.x;  // float4 groups
  int d4 = idx & 15;
  int t = (idx >> 4) & (T_SEQ - 1);
  int h = idx >> 16;
  const size_t CN4 = (size_t)NH * T_SEQ * HD / 4;
  float4 a = reinterpret_cast<const float4*>(Opart)[idx];
  float4 b = reinterpret_cast<const float4*>(Opart)[CN4 + idx];
  float l = lpart[h * T_SEQ + t] + lpart[NH * T_SEQ + h * T_SEQ + t];
  float inv = 1.0f / l;
  ushort4 u;
  u.x = f2bf((a.x + b.x) * inv); u.y = f2bf((a.y + b.y) * inv);
  u.z = f2bf((a.z + b.z) * inv); u.w = f2bf((a.w + b.w) * inv);
  *(ushort4*)(Ob + (size_t)t * C_EMB + h * HD + d4 * 4) = u;
}

// ---------------------------------------------------------------------------
// Path B (fallback for small ws): 2 chunks, bf16 partials (aliased buffers).
// ---------------------------------------------------------------------------
__global__ __launch_bounds__(256, 3) void attn_kernel2(
    const unsigned short* __restrict__ Q,
    const unsigned short* __restrict__ K,
    const unsigned short* __restrict__ Vt,
    unsigned short* __restrict__ Op0,
    unsigned short* __restrict__ Op1,
    float* __restrict__ lpart) {
  const int bid = blockIdx.x;               // 0..767
  const int h = bid % NH;
  const int z = bid / NH;
  const int qt = (T_SEQ / 128 - 1) - (z >> 1);
  const int c = z & 1;
  const int q0 = qt * 128;
  const int sb = c ? (qt + 1) : 0;
  const int se = c ? (2 * qt + 2) : (qt + 1);

  unsigned short* Oc = c ? Op1 : Op0;
  float* lc = lpart + (size_t)c * NH * T_SEQ;
  attn_body(Q, K, Vt, h, q0, sb, se,
    [&](const AttnState& st, int qrow_base, int lm, int lq) {
#pragma unroll
      for (int m = 0; m < 2; m++) {
        if (lq == 0) lc[h * T_SEQ + qrow_base + m * 16 + lm] = st.rsum[m];
#pragma unroll
        for (int r = 0; r < 4; r++) {
          int t = qrow_base + m * 16 + lq * 4 + r;
#pragma unroll
          for (int jd = 0; jd < 4; jd++)
            Oc[((size_t)h * T_SEQ + t) * HD + jd * 16 + lm] = f2bf(st.o_acc[m][jd][r]);
        }
      }
    });
}

__global__ void combine_kernel2(const unsigned short* __restrict__ Op0,
                                const unsigned short* __restrict__ Op1,
                                const float* __restrict__ lpart,
                                unsigned short* __restrict__ Ob) {
  int idx = blockIdx.x * blockDim.x + threadIdx.x;
  int d4 = idx & 15;
  int t = (idx >> 4) & (T_SEQ - 1);
  int h = idx >> 16;
  float l = lpart[h * T_SEQ + t] + lpart[NH * T_SEQ + h * T_SEQ + t];
  float inv = 1.0f / l;
  ushort4 a = reinterpret_cast<const ushort4*>(Op0)[idx];
  ushort4 b = reinterpret_cast<const ushort4*>(Op1)[idx];
  ushort4 u;
  u.x = f2bf((bf2f(a.x) + bf2f(b.x)) * inv);
  u.y = f2bf((bf2f(a.y) + bf2f(b.y)) * inv);
  u.z = f2bf((bf2f(a.z) + bf2f(b.z)) * inv);
  u.w = f2bf((bf2f(a.w) + bf2f(b.w)) * inv);
  *(ushort4*)(Ob + (size_t)t * C_EMB + h * HD + d4 * 4) = u;
}

// ---------------------------------------------------------------------------
// Output GEMM (R17): 64x128 tile, BK=64, 2-phase static-dbuf K-loop.
// out[m][n] = sum_k O[m][k]*Wo[n][k]  (M=4096, N=768, K=768)
// -> 64 x 6 = 384 blocks, 12 K-steps, LDS 48 KB. fp32 out.
// ---------------------------------------------------------------------------
__global__ __launch_bounds__(256) void gemm_out(
    const unsigned short* __restrict__ A,
    const unsigned short* __restrict__ B,
    float* __restrict__ Out) {
  constexpr int K = 768, BM = 64, BN = 128, BK = 64;
  __shared__ __align__(16) unsigned short As0[BM * BK];  // 8 KB
  __shared__ __align__(16) unsigned short Bs0[BN * BK];  // 16 KB
  __shared__ __align__(16) unsigned short As1[BM * BK];  // 8 KB
  __shared__ __align__(16) unsigned short Bs1[BN * BK];  // 16 KB
  const int tid = threadIdx.x;
  const int wave = tid >> 6, lane = tid & 63;
  const int lm = lane & 15, lq = lane >> 4;
  const int swz = lm & 7;
  const int m0 = blockIdx.x * BM, n0 = blockIdx.y * BN;
  const int wm = (wave & 1) * 32, wn = (wave >> 1) * 64;
  floatx4 acc[2][4] = {};

  auto stage = [&](int k0, unsigned short* Ad, unsigned short* Bd) {
#pragma unroll
    for (int i = 0; i < 2; i++) {
      int idx = i * 256 + tid;
      int row = idx >> 3;
      int ch = (idx & 7) ^ (row & 7);
      gload_lds16(A + (size_t)(m0 + row) * K + k0 + ch * 8, (char*)Ad + idx * 16);
    }
#pragma unroll
    for (int i = 0; i < 4; i++) {
      int idx = i * 256 + tid;
      int row = idx >> 3;
      int ch = (idx & 7) ^ (row & 7);
      gload_lds16(B + (size_t)(n0 + row) * K + k0 + ch * 8, (char*)Bd + idx * 16);
    }
  };

  auto compute = [&](const unsigned short* Asb, const unsigned short* Bsb) {
#pragma unroll
    for (int kk = 0; kk < 2; kk++) {
      bf16x8 af[2], bfr[4];
#pragma unroll
      for (int i = 0; i < 2; i++) {
        int row = wm + i * 16 + lm;
        af[i] = *(const bf16x8*)(Asb + row * BK + (((kk * 4 + lq) ^ swz) * 8));
      }
#pragma unroll
      for (int j = 0; j < 4; j++) {
        int row = wn + j * 16 + lm;
        bfr[j] = *(const bf16x8*)(Bsb + row * BK + (((kk * 4 + lq) ^ swz) * 8));
      }
#pragma unroll
      for (int i = 0; i < 2; i++)
#pragma unroll
        for (int j = 0; j < 4; j++)
          acc[i][j] = __builtin_amdgcn_mfma_f32_16x16x32_bf16(af[i], bfr[j], acc[i][j], 0, 0, 0);
    }
  };

  stage(0, As0, Bs0);
  int k0 = 0;
  while (true) {
    __syncthreads();                        // buf0 staged; buf1 reads done
    if (k0 + BK < K) stage(k0 + BK, As1, Bs1);
    compute(As0, Bs0);
    k0 += BK; if (k0 >= K) break;
    __syncthreads();                        // buf1 staged; buf0 reads done
    if (k0 + BK < K) stage(k0 + BK, As0, Bs0);
    compute(As1, Bs1);
    k0 += BK; if (k0 >= K) break;
  }

#pragma unroll
  for (int i = 0; i < 2; i++)
#pragma unroll
    for (int j = 0; j < 4; j++)
#pragma unroll
      for (int r = 0; r < 4; r++) {
        int m = m0 + wm + i * 16 + lq * 4 + r;
        int n = n0 + wn + j * 16 + lm;
        Out[(size_t)m * C_EMB + n] = acc[i][j][r];
      }
}

// ---------------------------------------------------------------------------
// Workspace layouts.
// Head (shorts): Xb[0,XN) | Wqkv[XN,XN+3WN) | Wob | Qb->Ob | Kb | Vt | tail.
// Path A (>= ~55.4 MB): fp32 Opart2+lpart2 in tail.
// Path B: Op0=dead Xb, lpart=dead Wqkv, Op1=tail (bf16). 36.18 MB total.
// ---------------------------------------------------------------------------
extern "C" void kernel_launch(void* const* d_in, const int* in_sizes, int n_in,
                              void* d_out, int out_size, void* d_ws, size_t ws_size,
                              hipStream_t stream) {
  const float* x  = (const float*)d_in[0];
  const float* wq = (const float*)d_in[1];
  const float* wk = (const float*)d_in[2];
  const float* wv = (const float*)d_in[3];
  const float* wo = (const float*)d_in[4];
  float* out = (float*)d_out;

  const size_t XN = (size_t)T_SEQ * C_EMB;      // 3,145,728 elems
  const size_t WN = (size_t)C_EMB * C_EMB;      //   589,824 elems
  unsigned short* base = (unsigned short*)d_ws;

  unsigned short* Xb   = base;
  unsigned short* Wqkv = base + XN;
  unsigned short* Wob  = base + XN + 3 * WN;
  unsigned short* Qb   = base + XN + 4 * WN;
  unsigned short* Kb   = Qb + XN;
  unsigned short* Vt   = Kb + XN;
  unsigned short* tail = Vt + XN;               // byte 29,884,416
  unsigned short* Ob   = Qb;                    // alias: Q dead after attn

  const size_t needA = 29884416ull + 2ull * XN * 4ull + 2ull * NH * T_SEQ * 4ull;  // ~55.4 MB

  const int ngroups = (int)((XN + 4 * WN) / 4); // 1,376,256
  cast_all_kernel<<<dim3(ngroups / 256), 256, 0, stream>>>(x, wq, wk, wv, wo, Xb);

  gemm_qkv<<<dim3(T_SEQ / 64, 2304 / 128), 256, 0, stream>>>(Xb, Wqkv, Qb, Kb, Vt);

  if (ws_size >= needA) {
    float* OpartA = (float*)tail;
    float* lpartA = OpartA + 2 * XN;
    attn_kernelA<<<dim3((T_SEQ / 128) * 2 * NH), 256, 0, stream>>>(Qb, Kb, Vt, OpartA, lpartA);
    combine_kernelA<<<dim3((int)(XN / 4) / 256), 256, 0, stream>>>(OpartA, lpartA, Ob);
  } else {
    unsigned short* Op0 = base;
    unsigned short* Op1 = tail;
    float* lpart = (float*)(base + XN);
    attn_kernel2<<<dim3((T_SEQ / 128) * 2 * NH), 256, 0, stream>>>(Qb, Kb, Vt, Op0, Op1, lpart);
    combine_kernel2<<<dim3((int)(XN / 4) / 256), 256, 0, stream>>>(Op0, Op1, lpart, Ob);
  }

  gemm_out<<<dim3(T_SEQ / 64, C_EMB / 128), 256, 0, stream>>>(Ob, Wob, out);
}

// Round 13
// 155.275 us; speedup vs baseline: 1.6854x; 1.6854x over previous
//
#include <hip/hip_runtime.h>

// ---------------------------------------------------------------------------
// Causal self-attention block, B=1 T=4096 C=768 H=12 D=64, fp32 in/out.
// bf16 MFMA everywhere; flash attention without online max (scores bounded,
// log2-domain) -> s-chunks combine by pure summation (NO atomics: R4/R5
// showed fp32 atomicAdd accumulation is nondeterministically wrong here;
// exclusive-slot partials are deterministic, proven R6/R7).
// R23 = exact revert to R21 (session best: 156.6 us).
// R22 post-mortem: macro-form deferred-PV STILL spilled (VGPR pinned 84,
// FETCH 15->103MB, attn 153us) - carrying 48 VGPRs of PV operands across
// __syncthreads() in a runtime-trip loop is spilled by the allocator
// regardless of source form (R19 lambda, R22 macro). Axis closed.
// R21: swapped-QK^T - sa = mfma(kf, qf) puts 4 CONSECUTIVE s-values for
// ONE q-row (q=m*16+lm, s=s0+j*16+lq*4+r) in each lane: P-writes are 8x
// ds_write_b64 (not 32x b16); rsum is 2 floats/lane, 2-shuffle reduction.
// Pipeline = R13 2-phase static dbuf; partials = R15 2-chunk fp32;
// GEMMs = R17 dbuf. Session: 166.7 -> 156.6 us (R13 +5%, R15 -50MB
// traffic, R21 +7%). Failed axes: dynamic dbuf idx (R11), direct-KV (R12),
// 128^2 qkv tile (R14), direct-V (R18), deferred-PV (R19/R22 spill wall).
// ---------------------------------------------------------------------------

#define T_SEQ 4096
#define C_EMB 768
#define NH    12
#define HD    64

typedef __attribute__((ext_vector_type(8))) short bf16x8;   // 8 bf16 = 4 VGPRs
typedef __attribute__((ext_vector_type(4))) float floatx4;  // MFMA C/D

// 0.125 (1/sqrt(64)) * log2(e): folded into Q so scores are log2-domain.
#define QSCALE 0.18033688011112042f

__device__ __forceinline__ unsigned short f2bf(float f) {
  union { float f; unsigned u; } v; v.f = f;
  unsigned r = v.u + 0x7fffu + ((v.u >> 16) & 1u);  // RNE
  return (unsigned short)(r >> 16);
}
// round-half-up, valid for f >= 0 (used for P probabilities)
__device__ __forceinline__ unsigned short f2bf_rhu(float f) {
  union { float f; unsigned u; } v; v.f = f;
  return (unsigned short)((v.u + 0x8000u) >> 16);
}
__device__ __forceinline__ float bf2f(unsigned short h) {
  union { unsigned u; float f; } v; v.u = ((unsigned)h) << 16;
  return v.f;
}

// async global->LDS, 16B/lane. LDS dest is wave-uniform base + lane*16.
__device__ __forceinline__ void gload_lds16(const void* gptr, void* ldsptr) {
  __builtin_amdgcn_global_load_lds(
      (const __attribute__((address_space(1))) unsigned int*)gptr,
      (__attribute__((address_space(3))) unsigned int*)ldsptr,
      16, 0, 0);
}

// ---------------------------------------------------------------------------
// Single fused cast (known-good): [x|wq|wk|wv|wo] fp32 -> contiguous bf16.
// ---------------------------------------------------------------------------
__global__ void cast_all_kernel(const float* __restrict__ x,
                                const float* __restrict__ wq,
                                const float* __restrict__ wk,
                                const float* __restrict__ wv,
                                const float* __restrict__ wo,
                                unsigned short* __restrict__ dst) {
  const int GX = (T_SEQ * C_EMB) / 4;
  const int GW = (C_EMB * C_EMB) / 4;
  int i = blockIdx.x * blockDim.x + threadIdx.x;
  const float* src; int local;
  if (i < GX) { src = x; local = i; }
  else {
    int t = i - GX; int w = t / GW; local = t - w * GW;
    src = (w == 0) ? wq : (w == 1) ? wk : (w == 2) ? wv : wo;
  }
  float4 f = reinterpret_cast<const float4*>(src)[local];
  ushort4 u;
  u.x = f2bf(f.x); u.y = f2bf(f.y); u.z = f2bf(f.z); u.w = f2bf(f.w);
  reinterpret_cast<ushort4*>(dst)[i] = u;
}

// ---------------------------------------------------------------------------
// QKV GEMM (R17): 64x128 tile, BK=64, 2-phase static-dbuf K-loop.
// C[m][n] = sum_k X[m][k]*Wqkv[n][k]  (M=4096, N=2304, K=768)
// -> 64 x 18 = 1152 blocks, 12 K-steps, LDS 48 KB (3 blocks/CU).
// Staging swizzle: 8 chunks/row, ch = (idx&7)^(row&7); fragment read at
// chunk (kk*4+lq)^(lm&7) (row&7 == lm&7 for all fragment rows).
// Epilogue: Q pre-scaled; V -> Vt[H][D][T], ushort4.
// ---------------------------------------------------------------------------
__global__ __launch_bounds__(256) void gemm_qkv(
    const unsigned short* __restrict__ A,
    const unsigned short* __restrict__ B,
    unsigned short* __restrict__ Qb,
    unsigned short* __restrict__ Kb,
    unsigned short* __restrict__ Vt) {
  constexpr int K = 768, BM = 64, BN = 128, BK = 64;
  __shared__ __align__(16) unsigned short As0[BM * BK];  // 8 KB
  __shared__ __align__(16) unsigned short Bs0[BN * BK];  // 16 KB
  __shared__ __align__(16) unsigned short As1[BM * BK];  // 8 KB
  __shared__ __align__(16) unsigned short Bs1[BN * BK];  // 16 KB
  const int tid = threadIdx.x;
  const int wave = tid >> 6, lane = tid & 63;
  const int lm = lane & 15, lq = lane >> 4;
  const int swz = lm & 7;
  const int m0 = blockIdx.x * BM, n0 = blockIdx.y * BN;
  const int wm = (wave & 1) * 32, wn = (wave >> 1) * 64;
  floatx4 acc[2][4] = {};

  auto stage = [&](int k0, unsigned short* Ad, unsigned short* Bd) {
#pragma unroll
    for (int i = 0; i < 2; i++) {             // A: 512 chunks (64 rows x 8)
      int idx = i * 256 + tid;
      int row = idx >> 3;
      int ch = (idx & 7) ^ (row & 7);
      gload_lds16(A + (size_t)(m0 + row) * K + k0 + ch * 8, (char*)Ad + idx * 16);
    }
#pragma unroll
    for (int i = 0; i < 4; i++) {             // B: 1024 chunks (128 rows x 8)
      int idx = i * 256 + tid;
      int row = idx >> 3;
      int ch = (idx & 7) ^ (row & 7);
      gload_lds16(B + (size_t)(n0 + row) * K + k0 + ch * 8, (char*)Bd + idx * 16);
    }
  };

  auto compute = [&](const unsigned short* Asb, const unsigned short* Bsb) {
#pragma unroll
    for (int kk = 0; kk < 2; kk++) {
      bf16x8 af[2], bfr[4];
#pragma unroll
      for (int i = 0; i < 2; i++) {
        int row = wm + i * 16 + lm;
        af[i] = *(const bf16x8*)(Asb + row * BK + (((kk * 4 + lq) ^ swz) * 8));
      }
#pragma unroll
      for (int j = 0; j < 4; j++) {
        int row = wn + j * 16 + lm;
        bfr[j] = *(const bf16x8*)(Bsb + row * BK + (((kk * 4 + lq) ^ swz) * 8));
      }
#pragma unroll
      for (int i = 0; i < 2; i++)
#pragma unroll
        for (int j = 0; j < 4; j++)
          acc[i][j] = __builtin_amdgcn_mfma_f32_16x16x32_bf16(af[i], bfr[j], acc[i][j], 0, 0, 0);
    }
  };

  // 2-phase static-dbuf pipeline (R13 transform): one barrier per K-step;
  // prefetch issued right after the barrier, drained at the NEXT barrier.
  stage(0, As0, Bs0);
  int k0 = 0;
  while (true) {
    __syncthreads();                        // buf0 staged; buf1 reads done
    if (k0 + BK < K) stage(k0 + BK, As1, Bs1);
    compute(As0, Bs0);
    k0 += BK; if (k0 >= K) break;
    __syncthreads();                        // buf1 staged; buf0 reads done
    if (k0 + BK < K) stage(k0 + BK, As0, Bs0);
    compute(As1, Bs1);
    k0 += BK; if (k0 >= K) break;
  }

  const int which = n0 / C_EMB;                   // block-uniform (128 | 768)
  if (which < 2) {
    unsigned short* tgt = (which == 0) ? Qb : Kb;
    const float sc = (which == 0) ? QSCALE : 1.0f;
#pragma unroll
    for (int i = 0; i < 2; i++)
#pragma unroll
      for (int j = 0; j < 4; j++) {
        int n = n0 - which * C_EMB + wn + j * 16 + lm;
        int h = n >> 6, d = n & 63;
#pragma unroll
        for (int r = 0; r < 4; r++) {
          int m = m0 + wm + i * 16 + lq * 4 + r;
          tgt[(((size_t)h * T_SEQ + m) << 6) + d] = f2bf(acc[i][j][r] * sc);
        }
      }
  } else {
#pragma unroll
    for (int i = 0; i < 2; i++)
#pragma unroll
      for (int j = 0; j < 4; j++) {
        int n = n0 - 2 * C_EMB + wn + j * 16 + lm;
        int h = n >> 6, d = n & 63;
        int m = m0 + wm + i * 16 + lq * 4;
        ushort4 pk;
        pk.x = f2bf(acc[i][j][0]); pk.y = f2bf(acc[i][j][1]);
        pk.z = f2bf(acc[i][j][2]); pk.w = f2bf(acc[i][j][3]);
        *(ushort4*)(Vt + ((size_t)(h * HD + d)) * T_SEQ + m) = pk;
      }
  }
}

// ---------------------------------------------------------------------------
// Shared attention inner body (R21): swapped-QK^T variant of the proven R13
// 2-phase static-dbuf pipeline. sa = mfma(kf, qf) -> lane holds
// P[q = m*16+lm][s = s0 + j*16 + lq*4 + r]: 4 consecutive s per (m,j),
// packed into one ds_write_b64 at Pw[(m*16+lm)*PS + j*16 + lq*4]. The P
// LDS layout (and the whole PV read path) is IDENTICAL to R13/R17.
// rsum: 2 floats/lane (per m), cross-lq reduction = shfl_xor 16,32.
// ---------------------------------------------------------------------------
struct AttnState {
  float rsum[2];
  floatx4 o_acc[2][4];
};

template <typename EpilogueFn>
__device__ __forceinline__ void attn_body(
    const unsigned short* __restrict__ Q,
    const unsigned short* __restrict__ K,
    const unsigned short* __restrict__ Vt,
    int h, int q0, int sb, int se,
    EpilogueFn epi) {
  constexpr int BS = 64, PS = 72, KVB = BS * HD;   // 4096 shorts per buffer
  __shared__ __align__(16) unsigned short Ks0[KVB];      // 8 KB
  __shared__ __align__(16) unsigned short Vs0[KVB];      // 8 KB
  __shared__ __align__(16) unsigned short Ks1[KVB];      // 8 KB
  __shared__ __align__(16) unsigned short Vs1[KVB];      // 8 KB
  __shared__ __align__(16) unsigned short Ps[4 * 32 * PS];  // 18 KB

  const int tid = threadIdx.x;
  const int wave = tid >> 6, lane = tid & 63;
  const int lm = lane & 15, lq = lane >> 4;
  const unsigned short* Qh = Q + (size_t)h * T_SEQ * HD;
  const unsigned short* Kh = K + (size_t)h * T_SEQ * HD;
  const unsigned short* Vh = Vt + (size_t)h * HD * T_SEQ;
  const int qrow_base = q0 + wave * 32;
  unsigned short* Pw = Ps + wave * 32 * PS;
  const int swz = lm & 7;

  bf16x8 qf[2][2];
#pragma unroll
  for (int m = 0; m < 2; m++)
#pragma unroll
    for (int kk = 0; kk < 2; kk++)
      qf[m][kk] = *(const bf16x8*)(Qh + (size_t)(qrow_base + m * 16 + lm) * HD + kk * 32 + lq * 8);

  AttnState st;
#pragma unroll
  for (int m = 0; m < 2; m++) {
    st.rsum[m] = 0.f;
#pragma unroll
    for (int r = 0; r < 4; r++) st.o_acc[m][r] = floatx4{0.f, 0.f, 0.f, 0.f};
  }

  auto stage = [&](int s0, unsigned short* Kd, unsigned short* Vd) {
#pragma unroll
    for (int i = 0; i < 2; i++) {
      int idx = (wave * 2 + i) * 64 + lane;
      int row = idx >> 3;
      int ch = (idx & 7) ^ (row & 7);
      gload_lds16(Kh + (size_t)(s0 + row) * HD + ch * 8, (char*)Kd + idx * 16);
      gload_lds16(Vh + (size_t)row * T_SEQ + s0 + ch * 8, (char*)Vd + idx * 16);
    }
  };

  auto compute = [&](int it, const unsigned short* Kc, const unsigned short* Vc) {
    const int s0 = it * BS;
    floatx4 sa[2][4] = {};
#pragma unroll
    for (int kk = 0; kk < 2; kk++)
#pragma unroll
      for (int j = 0; j < 4; j++) {
        int row = j * 16 + lm;
        bf16x8 kf = *(const bf16x8*)(Kc + (row * 8 + ((kk * 4 + lq) ^ swz)) * 8);
        // SWAPPED operands: D row (lq*4+r) = s within j-block, col (lm) = q.
#pragma unroll
        for (int m = 0; m < 2; m++)
          sa[m][j] = __builtin_amdgcn_mfma_f32_16x16x32_bf16(kf, qf[m][kk], sa[m][j], 0, 0, 0);
      }

    if (s0 >= q0) {                         // diagonal band: causal mask
#pragma unroll
      for (int m = 0; m < 2; m++) {
        int qrow = qrow_base + m * 16 + lm;
#pragma unroll
        for (int j = 0; j < 4; j++)
#pragma unroll
          for (int r = 0; r < 4; r++) {
            int scol = s0 + j * 16 + lq * 4 + r;
            if (scol > qrow) sa[m][j][r] = -1e30f;
          }
      }
    }

    // softmax + vectorized P store: per (m,j) one 8B write of 4 bf16.
#pragma unroll
    for (int m = 0; m < 2; m++)
#pragma unroll
      for (int j = 0; j < 4; j++) {
        float p0 = __builtin_amdgcn_exp2f(sa[m][j][0]);
        float p1 = __builtin_amdgcn_exp2f(sa[m][j][1]);
        float p2 = __builtin_amdgcn_exp2f(sa[m][j][2]);
        float p3 = __builtin_amdgcn_exp2f(sa[m][j][3]);
        st.rsum[m] += (p0 + p1) + (p2 + p3);
        ushort4 pk;
        pk.x = f2bf_rhu(p0); pk.y = f2bf_rhu(p1);
        pk.z = f2bf_rhu(p2); pk.w = f2bf_rhu(p3);
        *(ushort4*)(Pw + (m * 16 + lm) * PS + j * 16 + lq * 4) = pk;
      }

#pragma unroll
    for (int kk = 0; kk < 2; kk++) {
      bf16x8 pf[2];
#pragma unroll
      for (int m = 0; m < 2; m++)
        pf[m] = *(const bf16x8*)(Pw + (m * 16 + lm) * PS + kk * 32 + lq * 8);
#pragma unroll
      for (int jd = 0; jd < 4; jd++) {
        int row = jd * 16 + lm;
        bf16x8 vf = *(const bf16x8*)(Vc + (row * 8 + ((kk * 4 + lq) ^ swz)) * 8);
#pragma unroll
        for (int m = 0; m < 2; m++)
          st.o_acc[m][jd] = __builtin_amdgcn_mfma_f32_16x16x32_bf16(pf[m], vf, st.o_acc[m][jd], 0, 0, 0);
      }
    }
  };

  // 2-phase static-dbuf pipeline: one barrier per step; prefetch issued
  // immediately after the barrier, drained at the NEXT barrier.
  stage(sb * BS, Ks0, Vs0);
  int it = sb;
  while (true) {
    __syncthreads();                        // buf0 staged; buf1 reads done
    if (it + 1 < se) stage((it + 1) * BS, Ks1, Vs1);
    compute(it, Ks0, Vs0);
    if (++it >= se) break;
    __syncthreads();                        // buf1 staged; buf0 reads done
    if (it + 1 < se) stage((it + 1) * BS, Ks0, Vs0);
    compute(it, Ks1, Vs1);
    if (++it >= se) break;
  }

  // row-sum: per-lane partial covers s-cols {j*16+lq*4+r}; reduce across lq
#pragma unroll
  for (int m = 0; m < 2; m++) {
    float s = st.rsum[m];
    s += __shfl_xor(s, 16);
    s += __shfl_xor(s, 32);
    st.rsum[m] = s;
  }
  epi(st, qrow_base, lm, lq);
}

// ---------------------------------------------------------------------------
// Path A (R15, proven): 2 chunks, fp32 partials to exclusive slots.
// 768 blocks = exactly 3/CU (full residency); heavy q-tiles first.
// lpart store: rsum[m] lives in lanes by lm (q = qrow_base + m*16 + lm).
// ---------------------------------------------------------------------------
__global__ __launch_bounds__(256, 3) void attn_kernelA(
    const unsigned short* __restrict__ Q,
    const unsigned short* __restrict__ K,
    const unsigned short* __restrict__ Vt,
    float* __restrict__ Opart,              // [2][12][4096][64] fp32
    float* __restrict__ lpart) {            // [2][12][4096] fp32
  const int bid = blockIdx.x;               // 0..767
  const int h = bid % NH;
  const int z = bid / NH;                   // 0..63
  const int qt = (T_SEQ / 128 - 1) - (z >> 1);  // heavy tiles first
  const int c = z & 1;
  const int q0 = qt * 128;
  const int sb = c ? (qt + 1) : 0;
  const int se = c ? (2 * qt + 2) : (qt + 1);

  const size_t CN = (size_t)NH * T_SEQ * HD;
  float* Oc = Opart + (size_t)c * CN;
  float* lc = lpart + (size_t)c * NH * T_SEQ;
  attn_body(Q, K, Vt, h, q0, sb, se,
    [&](const AttnState& st, int qrow_base, int lm, int lq) {
#pragma unroll
      for (int m = 0; m < 2; m++) {
        if (lq == 0) lc[h * T_SEQ + qrow_base + m * 16 + lm] = st.rsum[m];
#pragma unroll
        for (int r = 0; r < 4; r++) {
          int t = qrow_base + m * 16 + lq * 4 + r;
#pragma unroll
          for (int jd = 0; jd < 4; jd++)
            Oc[((size_t)h * T_SEQ + t) * HD + jd * 16 + lm] = st.o_acc[m][jd][r];
        }
      }
    });
}

__global__ void combine_kernelA(const float* __restrict__ Opart,
                                const float* __restrict__ lpart,
                                unsigned short* __restrict__ Ob) {
  int idx = blockIdx.x * blockDim.x + threadIdx.x;  // float4 groups
  int d4 = idx & 15;
  int t = (idx >> 4) & (T_SEQ - 1);
  int h = idx >> 16;
  const size_t CN4 = (size_t)NH * T_SEQ * HD / 4;
  float4 a = reinterpret_cast<const float4*>(Opart)[idx];
  float4 b = reinterpret_cast<const float4*>(Opart)[CN4 + idx];
  float l = lpart[h * T_SEQ + t] + lpart[NH * T_SEQ + h * T_SEQ + t];
  float inv = 1.0f / l;
  ushort4 u;
  u.x = f2bf((a.x + b.x) * inv); u.y = f2bf((a.y + b.y) * inv);
  u.z = f2bf((a.z + b.z) * inv); u.w = f2bf((a.w + b.w) * inv);
  *(ushort4*)(Ob + (size_t)t * C_EMB + h * HD + d4 * 4) = u;
}

// ---------------------------------------------------------------------------
// Path B (fallback for small ws): 2 chunks, bf16 partials (aliased buffers).
// ---------------------------------------------------------------------------
__global__ __launch_bounds__(256, 3) void attn_kernel2(
    const unsigned short* __restrict__ Q,
    const unsigned short* __restrict__ K,
    const unsigned short* __restrict__ Vt,
    unsigned short* __restrict__ Op0,
    unsigned short* __restrict__ Op1,
    float* __restrict__ lpart) {
  const int bid = blockIdx.x;               // 0..767
  const int h = bid % NH;
  const int z = bid / NH;
  const int qt = (T_SEQ / 128 - 1) - (z >> 1);
  const int c = z & 1;
  const int q0 = qt * 128;
  const int sb = c ? (qt + 1) : 0;
  const int se = c ? (2 * qt + 2) : (qt + 1);

  unsigned short* Oc = c ? Op1 : Op0;
  float* lc = lpart + (size_t)c * NH * T_SEQ;
  attn_body(Q, K, Vt, h, q0, sb, se,
    [&](const AttnState& st, int qrow_base, int lm, int lq) {
#pragma unroll
      for (int m = 0; m < 2; m++) {
        if (lq == 0) lc[h * T_SEQ + qrow_base + m * 16 + lm] = st.rsum[m];
#pragma unroll
        for (int r = 0; r < 4; r++) {
          int t = qrow_base + m * 16 + lq * 4 + r;
#pragma unroll
          for (int jd = 0; jd < 4; jd++)
            Oc[((size_t)h * T_SEQ + t) * HD + jd * 16 + lm] = f2bf(st.o_acc[m][jd][r]);
        }
      }
    });
}

__global__ void combine_kernel2(const unsigned short* __restrict__ Op0,
                                const unsigned short* __restrict__ Op1,
                                const float* __restrict__ lpart,
                                unsigned short* __restrict__ Ob) {
  int idx = blockIdx.x * blockDim.x + threadIdx.x;
  int d4 = idx & 15;
  int t = (idx >> 4) & (T_SEQ - 1);
  int h = idx >> 16;
  float l = lpart[h * T_SEQ + t] + lpart[NH * T_SEQ + h * T_SEQ + t];
  float inv = 1.0f / l;
  ushort4 a = reinterpret_cast<const ushort4*>(Op0)[idx];
  ushort4 b = reinterpret_cast<const ushort4*>(Op1)[idx];
  ushort4 u;
  u.x = f2bf((bf2f(a.x) + bf2f(b.x)) * inv);
  u.y = f2bf((bf2f(a.y) + bf2f(b.y)) * inv);
  u.z = f2bf((bf2f(a.z) + bf2f(b.z)) * inv);
  u.w = f2bf((bf2f(a.w) + bf2f(b.w)) * inv);
  *(ushort4*)(Ob + (size_t)t * C_EMB + h * HD + d4 * 4) = u;
}

// ---------------------------------------------------------------------------
// Output GEMM (R17): 64x128 tile, BK=64, 2-phase static-dbuf K-loop.
// out[m][n] = sum_k O[m][k]*Wo[n][k]  (M=4096, N=768, K=768)
// -> 64 x 6 = 384 blocks, 12 K-steps, LDS 48 KB. fp32 out.
// ---------------------------------------------------------------------------
__global__ __launch_bounds__(256) void gemm_out(
    const unsigned short* __restrict__ A,
    const unsigned short* __restrict__ B,
    float* __restrict__ Out) {
  constexpr int K = 768, BM = 64, BN = 128, BK = 64;
  __shared__ __align__(16) unsigned short As0[BM * BK];  // 8 KB
  __shared__ __align__(16) unsigned short Bs0[BN * BK];  // 16 KB
  __shared__ __align__(16) unsigned short As1[BM * BK];  // 8 KB
  __shared__ __align__(16) unsigned short Bs1[BN * BK];  // 16 KB
  const int tid = threadIdx.x;
  const int wave = tid >> 6, lane = tid & 63;
  const int lm = lane & 15, lq = lane >> 4;
  const int swz = lm & 7;
  const int m0 = blockIdx.x * BM, n0 = blockIdx.y * BN;
  const int wm = (wave & 1) * 32, wn = (wave >> 1) * 64;
  floatx4 acc[2][4] = {};

  auto stage = [&](int k0, unsigned short* Ad, unsigned short* Bd) {
#pragma unroll
    for (int i = 0; i < 2; i++) {
      int idx = i * 256 + tid;
      int row = idx >> 3;
      int ch = (idx & 7) ^ (row & 7);
      gload_lds16(A + (size_t)(m0 + row) * K + k0 + ch * 8, (char*)Ad + idx * 16);
    }
#pragma unroll
    for (int i = 0; i < 4; i++) {
      int idx = i * 256 + tid;
      int row = idx >> 3;
      int ch = (idx & 7) ^ (row & 7);
      gload_lds16(B + (size_t)(n0 + row) * K + k0 + ch * 8, (char*)Bd + idx * 16);
    }
  };

  auto compute = [&](const unsigned short* Asb, const unsigned short* Bsb) {
#pragma unroll
    for (int kk = 0; kk < 2; kk++) {
      bf16x8 af[2], bfr[4];
#pragma unroll
      for (int i = 0; i < 2; i++) {
        int row = wm + i * 16 + lm;
        af[i] = *(const bf16x8*)(Asb + row * BK + (((kk * 4 + lq) ^ swz) * 8));
      }
#pragma unroll
      for (int j = 0; j < 4; j++) {
        int row = wn + j * 16 + lm;
        bfr[j] = *(const bf16x8*)(Bsb + row * BK + (((kk * 4 + lq) ^ swz) * 8));
      }
#pragma unroll
      for (int i = 0; i < 2; i++)
#pragma unroll
        for (int j = 0; j < 4; j++)
          acc[i][j] = __builtin_amdgcn_mfma_f32_16x16x32_bf16(af[i], bfr[j], acc[i][j], 0, 0, 0);
    }
  };

  stage(0, As0, Bs0);
  int k0 = 0;
  while (true) {
    __syncthreads();                        // buf0 staged; buf1 reads done
    if (k0 + BK < K) stage(k0 + BK, As1, Bs1);
    compute(As0, Bs0);
    k0 += BK; if (k0 >= K) break;
    __syncthreads();                        // buf1 staged; buf0 reads done
    if (k0 + BK < K) stage(k0 + BK, As0, Bs0);
    compute(As1, Bs1);
    k0 += BK; if (k0 >= K) break;
  }

#pragma unroll
  for (int i = 0; i < 2; i++)
#pragma unroll
    for (int j = 0; j < 4; j++)
#pragma unroll
      for (int r = 0; r < 4; r++) {
        int m = m0 + wm + i * 16 + lq * 4 + r;
        int n = n0 + wn + j * 16 + lm;
        Out[(size_t)m * C_EMB + n] = acc[i][j][r];
      }
}

// ---------------------------------------------------------------------------
// Workspace layouts.
// Head (shorts): Xb[0,XN) | Wqkv[XN,XN+3WN) | Wob | Qb->Ob | Kb | Vt | tail.
// Path A (>= ~55.4 MB): fp32 Opart2+lpart2 in tail.
// Path B: Op0=dead Xb, lpart=dead Wqkv, Op1=tail (bf16). 36.18 MB total.
// ---------------------------------------------------------------------------
extern "C" void kernel_launch(void* const* d_in, const int* in_sizes, int n_in,
                              void* d_out, int out_size, void* d_ws, size_t ws_size,
                              hipStream_t stream) {
  const float* x  = (const float*)d_in[0];
  const float* wq = (const float*)d_in[1];
  const float* wk = (const float*)d_in[2];
  const float* wv = (const float*)d_in[3];
  const float* wo = (const float*)d_in[4];
  float* out = (float*)d_out;

  const size_t XN = (size_t)T_SEQ * C_EMB;      // 3,145,728 elems
  const size_t WN = (size_t)C_EMB * C_EMB;      //   589,824 elems
  unsigned short* base = (unsigned short*)d_ws;

  unsigned short* Xb   = base;
  unsigned short* Wqkv = base + XN;
  unsigned short* Wob  = base + XN + 3 * WN;
  unsigned short* Qb   = base + XN + 4 * WN;
  unsigned short* Kb   = Qb + XN;
  unsigned short* Vt   = Kb + XN;
  unsigned short* tail = Vt + XN;               // byte 29,884,416
  unsigned short* Ob   = Qb;                    // alias: Q dead after attn

  const size_t needA = 29884416ull + 2ull * XN * 4ull + 2ull * NH * T_SEQ * 4ull;  // ~55.4 MB

  const int ngroups = (int)((XN + 4 * WN) / 4); // 1,376,256
  cast_all_kernel<<<dim3(ngroups / 256), 256, 0, stream>>>(x, wq, wk, wv, wo, Xb);

  gemm_qkv<<<dim3(T_SEQ / 64, 2304 / 128), 256, 0, stream>>>(Xb, Wqkv, Qb, Kb, Vt);

  if (ws_size >= needA) {
    float* OpartA = (float*)tail;
    float* lpartA = OpartA + 2 * XN;
    attn_kernelA<<<dim3((T_SEQ / 128) * 2 * NH), 256, 0, stream>>>(Qb, Kb, Vt, OpartA, lpartA);
    combine_kernelA<<<dim3((int)(XN / 4) / 256), 256, 0, stream>>>(OpartA, lpartA, Ob);
  } else {
    unsigned short* Op0 = base;
    unsigned short* Op1 = tail;
    float* lpart = (float*)(base + XN);
    attn_kernel2<<<dim3((T_SEQ / 128) * 2 * NH), 256, 0, stream>>>(Qb, Kb, Vt, Op0, Op1, lpart);
    combine_kernel2<<<dim3((int)(XN / 4) / 256), 256, 0, stream>>>(Op0, Op1, lpart, Ob);
  }

  gemm_out<<<dim3(T_SEQ / 64, C_EMB / 128), 256, 0, stream>>>(Ob, Wob, out);
}